// Round 17
// baseline (289.290 us; speedup 1.0000x reference)
//
#include <hip/hip_runtime.h>
#include <math.h>

#define NEG_SLOPE 0.2f

typedef __attribute__((ext_vector_type(8))) short short8;
typedef __attribute__((ext_vector_type(4))) float f32x4;
typedef unsigned int uintx2 __attribute__((ext_vector_type(2)));
typedef unsigned int uintx4 __attribute__((ext_vector_type(4)));

__device__ __forceinline__ float leaky(float x) { return x > 0.f ? x : NEG_SLOPE * x; }
__device__ __forceinline__ unsigned enc(float f) {
    unsigned u = __float_as_uint(f);
    return (u & 0x80000000u) ? ~u : (u | 0x80000000u);
}
__device__ __forceinline__ float dec(unsigned e) {
    return (e & 0x80000000u) ? __uint_as_float(e ^ 0x80000000u) : __uint_as_float(~e);
}
__device__ __forceinline__ unsigned bf16u(float f) {
    unsigned u = __float_as_uint(f);
    return (u + 0x7fffu + ((u >> 16) & 1u)) >> 16;
}
__device__ __forceinline__ float blo(unsigned u) { return __uint_as_float(u << 16); }
__device__ __forceinline__ float bhi(unsigned u) { return __uint_as_float(u & 0xffff0000u); }

// ---- prep: W0 -> panel-major bf16 W0P[8][256][32] | [W1|Wres]^T -> Bt1 | count ---
__global__ __launch_bounds__(256) void prep_kernel(const float* __restrict__ W0,
                                                   unsigned short* __restrict__ W0P,
                                                   const float* __restrict__ W1,
                                                   const float* __restrict__ Wres,
                                                   unsigned short* __restrict__ Bt1,
                                                   const int* __restrict__ dst,
                                                   int* __restrict__ deg, int E) {
    int b = blockIdx.x, tid = threadIdx.x;
    if (b < 256) {                        // W0P[k>>5][n][k&31] = W0[k][n]
        int n = b, k = tid;
        W0P[(k >> 5) * 8192 + n * 32 + (k & 31)] = (unsigned short)bf16u(W0[k * 256 + n]);
    } else if (b < 320) {                 // Bt1[n][k]
        int n = b - 256, k = tid;
        float v = (n < 32) ? W1[k * 32 + n] : Wres[k * 32 + (n - 32)];
        Bt1[n * 256 + k] = (unsigned short)bf16u(v);
    } else {                              // degree count
        int e = (b - 320) * 256 + tid;
        if (e < E) atomicAdd(&deg[dst[e]], 1);
    }
}

// ---- layer0 GEMM (r16 structure) + A-ONLY prefetch (8 raw floats held; B in-loop).
//      B is L2-resident (cheap); A is the HBM-latency operand -> hide only A. -----
__global__ __launch_bounds__(256) void gemm0_all(const float* __restrict__ x,
                                                 const unsigned short* __restrict__ W0P,
                                                 unsigned short* __restrict__ featS,
                                                 float* __restrict__ el0, float* __restrict__ er0,
                                                 const float* __restrict__ al,
                                                 const float* __restrict__ ar,
                                                 unsigned* __restrict__ gmax, int M) {
    __shared__ unsigned short As[64 * 40];
    __shared__ unsigned short Bs[256 * 40];     // K-loop B; epilogue: aliased as tile[64*72]
    __shared__ float sEl[4][64], sEr[4][64];
    unsigned short* tile = Bs;                  // alias: Bs dead after K-loop
    const int K = 256;
    int tid = threadIdx.x, lane = tid & 63, wv = tid >> 6;
    int m0 = blockIdx.x * 64;
    int wm = (wv >> 1) * 32, wn = (wv & 1) * 32;
    f32x4 acc[4][2][2] = {};
    int arow = tid >> 2, apart = tid & 3;
    bool avalid = (m0 + arow) < M;
    const float* Ap = x + (size_t)min(m0 + arow, M - 1) * K + apart * 8;
    const float4 z4 = make_float4(0.f, 0.f, 0.f, 0.f);

    // preload A for k0 = 0 (raw fp32, packed at loop top)
    float4 a0n = avalid ? *(const float4*)Ap : z4;
    float4 a1n = avalid ? *(const float4*)(Ap + 4) : z4;

    for (int k0 = 0; k0 < K; k0 += 32) {
        // pack the prefetched A and stage to LDS
        uint4 ap;
        ap.x = bf16u(a0n.x) | (bf16u(a0n.y) << 16);
        ap.y = bf16u(a0n.z) | (bf16u(a0n.w) << 16);
        ap.z = bf16u(a1n.x) | (bf16u(a1n.y) << 16);
        ap.w = bf16u(a1n.z) | (bf16u(a1n.w) << 16);
        *(uint4*)&As[arow * 40 + apart * 8] = ap;
        // B: coalesced 16KB panel (k-slab) -> Bs (L2-resident, in-loop)
        const unsigned short* slab = W0P + (k0 >> 5) * 8192;
#pragma unroll
        for (int p = 0; p < 4; ++p) {
            int q = p * 256 + tid;
            uint4 bv = *(const uint4*)(slab + q * 8);
            *(uint4*)&Bs[(q >> 2) * 40 + (q & 3) * 8] = bv;
        }
        __syncthreads();
        // prefetch next A (HBM latency hides under MFMA section below)
        if (k0 + 32 < K) {
            a0n = avalid ? *(const float4*)(Ap + k0 + 32) : z4;
            a1n = avalid ? *(const float4*)(Ap + k0 + 36) : z4;
        }
        short8 af[2];
#pragma unroll
        for (int i = 0; i < 2; ++i)
            af[i] = *(const short8*)&As[(wm + i * 16 + (lane & 15)) * 40 + (lane >> 4) * 8];
#pragma unroll
        for (int y = 0; y < 4; ++y) {
            short8 bf[2];
#pragma unroll
            for (int j = 0; j < 2; ++j)
                bf[j] = *(const short8*)&Bs[(y * 64 + wn + j * 16 + (lane & 15)) * 40 + (lane >> 4) * 8];
#pragma unroll
            for (int i = 0; i < 2; ++i)
#pragma unroll
                for (int j = 0; j < 2; ++j)
                    acc[y][i][j] = __builtin_amdgcn_mfma_f32_16x16x32_bf16(af[i], bf[j], acc[y][i][j], 0, 0, 0);
        }
        __syncthreads();
    }
    size_t N32 = (size_t)M * 32;
#pragma unroll
    for (int y = 0; y < 4; ++y) {
#pragma unroll
        for (int i = 0; i < 2; ++i)
#pragma unroll
            for (int j = 0; j < 2; ++j)
#pragma unroll
                for (int r = 0; r < 4; ++r)
                    tile[(wm + i * 16 + (lane >> 4) * 4 + r) * 72 + wn + j * 16 + (lane & 15)] =
                        (unsigned short)bf16u(acc[y][i][j][r]);
        __syncthreads();
#pragma unroll
        for (int u = tid; u < 512; u += 256) {
            int ch = u >> 8, node = (u >> 2) & 63, part = u & 3;
            int row = m0 + node;
            if (row < M) {
                uint4 v = *(const uint4*)&tile[node * 72 + ch * 32 + part * 8];
                *(uint4*)&featS[(size_t)(2 * y + ch) * N32 + (size_t)row * 32 + part * 8] = v;
            }
        }
        {
            int row = tid >> 2, qr = tid & 3;
            float pe = 0.f, pr = 0.f;
            for (int k2 = 0; k2 < 16; ++k2) {
                int c = qr * 16 + k2;
                float f = __uint_as_float((unsigned)tile[row * 72 + c] << 16);
                pe += f * al[y * 64 + c];
                pr += f * ar[y * 64 + c];
            }
            pe += __shfl_xor(pe, 1); pe += __shfl_xor(pe, 2);
            pr += __shfl_xor(pr, 1); pr += __shfl_xor(pr, 2);
            if (qr == 0) {
                bool vv = (m0 + row) < M;
                if (vv) {
                    el0[(m0 + row) * 4 + y] = pe;
                    er0[(m0 + row) * 4 + y] = pr;
                }
                sEl[y][row] = vv ? pe : -1e30f;
                sEr[y][row] = vv ? pr : -1e30f;
            }
        }
        __syncthreads();
    }
    {
        float m1 = sEl[wv][lane];
        float m2 = sEr[wv][lane];
#pragma unroll
        for (int o = 1; o <= 32; o <<= 1) {
            m1 = fmaxf(m1, __shfl_xor(m1, o));
            m2 = fmaxf(m2, __shfl_xor(m2, o));
        }
        if (lane == 0) atomicMax(&gmax[wv], enc(m1));
        if (lane == 1) atomicMax(&gmax[4 + wv], enc(m2));
    }
}

// ---- layer1 GEMM (round-8 version VERBATIM) --------------------------------------
__global__ __launch_bounds__(256) void gemm1_fused(const unsigned short* __restrict__ hbS,
                                                   const unsigned short* __restrict__ Bt,
                                                   float* __restrict__ fcat,
                                                   unsigned short* __restrict__ fg16,
                                                   float* __restrict__ el1, float* __restrict__ er1,
                                                   const float* __restrict__ al,
                                                   const float* __restrict__ ar,
                                                   unsigned* __restrict__ gmax, int M) {
    __shared__ unsigned short As[64 * 40];
    __shared__ unsigned short Bs[64 * 40];
    __shared__ __align__(16) float tileF[64 * 68];
    __shared__ float sEl[64], sEr[64];
    const int K = 256;
    int tid = threadIdx.x, lane = tid & 63, wv = tid >> 6;
    int m0 = blockIdx.x * 64;
    int wm = (wv >> 1) * 32, wn = (wv & 1) * 32;
    f32x4 acc[2][2] = {};
    int srow = tid >> 2, scol = (tid & 3) * 8;
    bool avalid = (m0 + srow) < M;
    size_t arow = (size_t)min(m0 + srow, M - 1);
    size_t N32 = (size_t)M * 32;
    const unsigned short* Bp = Bt + (size_t)srow * K + scol;

    for (int k0 = 0; k0 < K; k0 += 32) {
        const unsigned short* Ap = hbS + (size_t)(k0 >> 5) * N32 + arow * 32 + scol;
        uint4 av = avalid ? *(const uint4*)Ap : make_uint4(0, 0, 0, 0);
        float4 bv = *(const float4*)(Bp + k0);
        *(uint4*)&As[srow * 40 + scol] = av;
        *(float4*)&Bs[srow * 40 + scol] = bv;
        __syncthreads();
        short8 af[2], bf[2];
#pragma unroll
        for (int i = 0; i < 2; ++i) {
            af[i] = *(const short8*)&As[(wm + i * 16 + (lane & 15)) * 40 + (lane >> 4) * 8];
            bf[i] = *(const short8*)&Bs[(wn + i * 16 + (lane & 15)) * 40 + (lane >> 4) * 8];
        }
#pragma unroll
        for (int i = 0; i < 2; ++i)
#pragma unroll
            for (int j = 0; j < 2; ++j)
                acc[i][j] = __builtin_amdgcn_mfma_f32_16x16x32_bf16(af[i], bf[j], acc[i][j], 0, 0, 0);
        __syncthreads();
    }
#pragma unroll
    for (int i = 0; i < 2; ++i)
#pragma unroll
        for (int j = 0; j < 2; ++j)
#pragma unroll
            for (int r = 0; r < 4; ++r)
                tileF[(wm + i * 16 + (lane >> 4) * 4 + r) * 68 + wn + j * 16 + (lane & 15)] =
                    acc[i][j][r];
    __syncthreads();
#pragma unroll
    for (int u = tid; u < 1024; u += 256) {
        int node = u >> 4, part = u & 15;
        int row = m0 + node;
        if (row < M)
            *(uint4*)&fcat[(size_t)row * 64 + part * 4] = *(const uint4*)&tileF[node * 68 + part * 4];
    }
    // fg16: bf16 copy of attended cols 0..31 (gather table for agg1)
#pragma unroll
    for (int u = tid; u < 1024; u += 256) {
        int node = u >> 4, part = u & 15;
        int row = m0 + node;
        if (row < M) {
            float f0 = tileF[node * 68 + part * 2];
            float f1 = tileF[node * 68 + part * 2 + 1];
            ((unsigned*)fg16)[(size_t)row * 16 + part] = bf16u(f0) | (bf16u(f1) << 16);
        }
    }
    {
        int row = tid >> 2, qr = tid & 3;
        float pe = 0.f, pr = 0.f;
        for (int k = 0; k < 8; ++k) {
            int c = qr * 8 + k;
            float f = tileF[row * 68 + c];
            pe += f * al[c];
            pr += f * ar[c];
        }
        pe += __shfl_xor(pe, 1); pe += __shfl_xor(pe, 2);
        pr += __shfl_xor(pr, 1); pr += __shfl_xor(pr, 2);
        if (qr == 0) {
            bool vv = (m0 + row) < M;
            if (vv) {
                el1[m0 + row] = pe;
                er1[m0 + row] = pr;
            }
            sEl[row] = vv ? pe : -1e30f;
            sEr[row] = vv ? pr : -1e30f;
        }
    }
    __syncthreads();
    if (tid < 64) {
        float m = sEl[tid];
#pragma unroll
        for (int o = 1; o <= 32; o <<= 1) m = fmaxf(m, __shfl_xor(m, o));
        if (tid == 0) atomicMax(&gmax[8], enc(m));
    } else if (tid < 128) {
        float m = sEr[tid - 64];
#pragma unroll
        for (int o = 1; o <= 32; o <<= 1) m = fmaxf(m, __shfl_xor(m, o));
        if (tid == 64) atomicMax(&gmax[9], enc(m));
    }
}

// ------------- CSR scans + scatter ------------------------------------------------
__global__ __launch_bounds__(256) void scanA(const int* __restrict__ deg, int* __restrict__ bsum, int N) {
    int i = blockIdx.x * 256 + threadIdx.x;
    int v = (i < N) ? deg[i] : 0;
#pragma unroll
    for (int o = 32; o > 0; o >>= 1) v += __shfl_xor(v, o);
    __shared__ int s[4];
    if ((threadIdx.x & 63) == 0) s[threadIdx.x >> 6] = v;
    __syncthreads();
    if (threadIdx.x == 0) bsum[blockIdx.x] = s[0] + s[1] + s[2] + s[3];
}

__global__ __launch_bounds__(256) void scanB(const int* __restrict__ bsum, int* __restrict__ bpre, int nb) {
    __shared__ int s[256];
    int t = threadIdx.x;
    int v = (t < nb) ? bsum[t] : 0;
    s[t] = v;
    __syncthreads();
    for (int o = 1; o < 256; o <<= 1) {
        int x = (t >= o) ? s[t - o] : 0;
        __syncthreads();
        s[t] += x;
        __syncthreads();
    }
    if (t < nb) bpre[t] = s[t] - v;
}

__global__ __launch_bounds__(256) void scanC(const int* __restrict__ deg, const int* __restrict__ bpre,
                                             int* __restrict__ off, int N) {
    int b = blockIdx.x, t = threadIdx.x;
    int i = b * 256 + t;
    int v = (i < N) ? deg[i] : 0;
    __shared__ int s[256];
    s[t] = v;
    __syncthreads();
    for (int o = 1; o < 256; o <<= 1) {
        int x = (t >= o) ? s[t - o] : 0;
        __syncthreads();
        s[t] += x;
        __syncthreads();
    }
    int incl = s[t];
    int base = bpre[b];
    if (i < N) off[i] = base + incl - v;
    if (i == N - 1) off[N] = base + incl;
}

__global__ void scatter_kernel(const int* __restrict__ src, const int* __restrict__ dst,
                               const int* __restrict__ off, int* __restrict__ cursor,
                               int* __restrict__ csr_src, int E) {
    int e = blockIdx.x * 256 + threadIdx.x;
    if (e < E) {
        int d = dst[e];
        int pos = atomicAdd(&cursor[d], 1);
        csr_src[off[d] + pos] = src[e];
    }
}

// ---- layer0 packed weights: pk0[h][idx] = (s<<16)|bf16(w); dinv per node/head ----
__global__ __launch_bounds__(256) void w0norm(const float* __restrict__ el,
                                              const float* __restrict__ er,
                                              const unsigned* __restrict__ gmax,
                                              const int* __restrict__ off,
                                              const int* __restrict__ csr_src,
                                              unsigned* __restrict__ pk0,
                                              float* __restrict__ dinv0, int N, int E) {
    int tid = threadIdx.x, lane = tid & 63, wv = tid >> 6;
    int grp = lane >> 4, j = lane & 15;
    float C0 = leaky(dec(gmax[0]) + dec(gmax[4]));
    float C1 = leaky(dec(gmax[1]) + dec(gmax[5]));
    float C2 = leaky(dec(gmax[2]) + dec(gmax[6]));
    float C3 = leaky(dec(gmax[3]) + dec(gmax[7]));
    int n = blockIdx.x * 16 + wv * 4 + grp;
    if (n >= N) return;
    int base = off[n], deg = off[n + 1] - base;
    float4 ern = *(const float4*)&er[n * 4];
    float d0 = 0.f, d1 = 0.f, d2 = 0.f, d3 = 0.f;
    for (int j0 = 0; j0 < deg; j0 += 16) {
        int jj = j0 + j;
        if (jj < deg) {
            int idx = base + jj;
            int s = csr_src[idx];
            float4 e4 = *(const float4*)&el[s * 4];
            unsigned b0 = bf16u(__expf(leaky(e4.x + ern.x) - C0));
            unsigned b1 = bf16u(__expf(leaky(e4.y + ern.y) - C1));
            unsigned b2 = bf16u(__expf(leaky(e4.z + ern.z) - C2));
            unsigned b3 = bf16u(__expf(leaky(e4.w + ern.w) - C3));
            unsigned sh = (unsigned)s << 16;
            pk0[idx] = sh | b0;
            pk0[E + idx] = sh | b1;
            pk0[2 * E + idx] = sh | b2;
            pk0[3 * E + idx] = sh | b3;
            d0 += __uint_as_float(b0 << 16);
            d1 += __uint_as_float(b1 << 16);
            d2 += __uint_as_float(b2 << 16);
            d3 += __uint_as_float(b3 << 16);
        }
    }
#pragma unroll
    for (int o = 1; o <= 8; o <<= 1) {
        d0 += __shfl_xor(d0, o);
        d1 += __shfl_xor(d1, o);
        d2 += __shfl_xor(d2, o);
        d3 += __shfl_xor(d3, o);
    }
    if (j == 0) {
        float4 iv = make_float4(1.f / d0, 1.f / d1, 1.f / d2, 1.f / d3);
        *(float4*)&dinv0[n * 4] = iv;
    }
}

// ---- layer1 packed weights: pk1[idx] = (s<<16)|bf16(w) --------------------------
__global__ __launch_bounds__(256) void w1norm(const float* __restrict__ el,
                                              const float* __restrict__ er,
                                              const unsigned* __restrict__ gmax,
                                              const int* __restrict__ off,
                                              const int* __restrict__ csr_src,
                                              unsigned* __restrict__ pk1,
                                              float* __restrict__ dinv1, int N) {
    int tid = threadIdx.x, lane = tid & 63, wv = tid >> 6;
    float C = leaky(dec(gmax[8]) + dec(gmax[9]));
    int n = blockIdx.x * 4 + wv;
    if (n >= N) return;
    int base = off[n], deg = off[n + 1] - base;
    float ern = er[n];
    float den = 0.f;
    for (int j0 = 0; j0 < deg; j0 += 64) {
        int jj = j0 + lane;
        if (jj < deg) {
            int idx = base + jj;
            int s = csr_src[idx];
            unsigned b = bf16u(__expf(leaky(el[s] + ern) - C));
            pk1[idx] = ((unsigned)s << 16) | b;
            den += __uint_as_float(b << 16);
        }
    }
#pragma unroll
    for (int o = 1; o <= 32; o <<= 1) den += __shfl_xor(den, o);
    if (lane == 0) dinv1[n] = 1.f / den;
}

// ---- layer0 aggregation: 4-lane group per node-chunk; packed pk; 4x unroll ------
__global__ __launch_bounds__(256) void agg0_kernel(const unsigned short* __restrict__ featS,
                                                   const unsigned* __restrict__ pk0,
                                                   const float* __restrict__ dinv0,
                                                   const int* __restrict__ off,
                                                   unsigned short* __restrict__ hbS, int N, int E) {
    int tid = threadIdx.x;
    int c = blockIdx.x & 7, h = c >> 1;
    int gblk = blockIdx.x >> 3, G = gridDim.x >> 3;
    int grp = tid >> 2, ld = tid & 3;    // 64 groups x 4 lanes; lane covers 8 dims
    size_t N32 = (size_t)N * 32;
    const char* Fb = (const char*)(featS + (size_t)c * N32) + ld * 16;
    const unsigned* PH = pk0 + (size_t)h * E;
    for (int n = gblk * 64 + grp; n < N; n += G * 64) {
        int base = off[n], deg = off[n + 1] - base;
        float a0 = 0.f, a1 = 0.f, a2 = 0.f, a3 = 0.f;
        float a4 = 0.f, a5 = 0.f, a6 = 0.f, a7 = 0.f;
        const unsigned* P = PH + base;
        int j = 0;
        for (; j + 4 <= deg; j += 4) {
            unsigned p0 = P[j], p1 = P[j + 1], p2 = P[j + 2], p3 = P[j + 3];
            uintx4 u0 = *(const uintx4*)(Fb + (size_t)(p0 >> 16) * 64);
            uintx4 u1 = *(const uintx4*)(Fb + (size_t)(p1 >> 16) * 64);
            uintx4 u2 = *(const uintx4*)(Fb + (size_t)(p2 >> 16) * 64);
            uintx4 u3 = *(const uintx4*)(Fb + (size_t)(p3 >> 16) * 64);
            float w0 = blo(p0), w1 = blo(p1), w2 = blo(p2), w3 = blo(p3);
            a0 += w0 * blo(u0.x); a1 += w0 * bhi(u0.x);
            a2 += w0 * blo(u0.y); a3 += w0 * bhi(u0.y);
            a4 += w0 * blo(u0.z); a5 += w0 * bhi(u0.z);
            a6 += w0 * blo(u0.w); a7 += w0 * bhi(u0.w);
            a0 += w1 * blo(u1.x); a1 += w1 * bhi(u1.x);
            a2 += w1 * blo(u1.y); a3 += w1 * bhi(u1.y);
            a4 += w1 * blo(u1.z); a5 += w1 * bhi(u1.z);
            a6 += w1 * blo(u1.w); a7 += w1 * bhi(u1.w);
            a0 += w2 * blo(u2.x); a1 += w2 * bhi(u2.x);
            a2 += w2 * blo(u2.y); a3 += w2 * bhi(u2.y);
            a4 += w2 * blo(u2.z); a5 += w2 * bhi(u2.z);
            a6 += w2 * blo(u2.w); a7 += w2 * bhi(u2.w);
            a0 += w3 * blo(u3.x); a1 += w3 * bhi(u3.x);
            a2 += w3 * blo(u3.y); a3 += w3 * bhi(u3.y);
            a4 += w3 * blo(u3.z); a5 += w3 * bhi(u3.z);
            a6 += w3 * blo(u3.w); a7 += w3 * bhi(u3.w);
        }
        for (; j < deg; ++j) {
            unsigned p = P[j];
            float w = blo(p);
            uintx4 u = *(const uintx4*)(Fb + (size_t)(p >> 16) * 64);
            a0 += w * blo(u.x); a1 += w * bhi(u.x);
            a2 += w * blo(u.y); a3 += w * bhi(u.y);
            a4 += w * blo(u.z); a5 += w * bhi(u.z);
            a6 += w * blo(u.w); a7 += w * bhi(u.w);
        }
        float inv = dinv0[n * 4 + h];
        float v0 = a0 * inv, v1 = a1 * inv, v2 = a2 * inv, v3 = a3 * inv;
        float v4 = a4 * inv, v5 = a5 * inv, v6 = a6 * inv, v7 = a7 * inv;
        v0 = v0 > 0.f ? v0 : (__expf(v0) - 1.f);
        v1 = v1 > 0.f ? v1 : (__expf(v1) - 1.f);
        v2 = v2 > 0.f ? v2 : (__expf(v2) - 1.f);
        v3 = v3 > 0.f ? v3 : (__expf(v3) - 1.f);
        v4 = v4 > 0.f ? v4 : (__expf(v4) - 1.f);
        v5 = v5 > 0.f ? v5 : (__expf(v5) - 1.f);
        v6 = v6 > 0.f ? v6 : (__expf(v6) - 1.f);
        v7 = v7 > 0.f ? v7 : (__expf(v7) - 1.f);
        uintx4 o;
        o.x = bf16u(v0) | (bf16u(v1) << 16);
        o.y = bf16u(v2) | (bf16u(v3) << 16);
        o.z = bf16u(v4) | (bf16u(v5) << 16);
        o.w = bf16u(v6) | (bf16u(v7) << 16);
        __builtin_nontemporal_store(o, (uintx4*)&hbS[(size_t)c * N32 + (size_t)n * 32 + ld * 8]);
    }
}

// ---- layer1 aggregation + residual: 8-lane group per node, packed pk ------------
__global__ __launch_bounds__(256) void agg1_kernel(const float* __restrict__ fcat,
                                                   const unsigned short* __restrict__ fg16,
                                                   const unsigned* __restrict__ pk1,
                                                   const float* __restrict__ dinv1,
                                                   const int* __restrict__ off,
                                                   float* __restrict__ out, int N) {
    int tid = threadIdx.x;
    int grp = tid >> 3, ld = tid & 7;    // 32 groups x 8 lanes; lane covers 4 dims
    const char* Fb = (const char*)fg16 + ld * 8;
    for (int n = blockIdx.x * 32 + grp; n < N; n += gridDim.x * 32) {
        int base = off[n], deg = off[n + 1] - base;
        float a0 = 0.f, a1 = 0.f, a2 = 0.f, a3 = 0.f;
        const unsigned* P = pk1 + base;
        int j = 0;
        for (; j + 4 <= deg; j += 4) {
            unsigned p0 = P[j], p1 = P[j + 1], p2 = P[j + 2], p3 = P[j + 3];
            uintx2 u0 = *(const uintx2*)(Fb + (size_t)(p0 >> 16) * 64);
            uintx2 u1 = *(const uintx2*)(Fb + (size_t)(p1 >> 16) * 64);
            uintx2 u2 = *(const uintx2*)(Fb + (size_t)(p2 >> 16) * 64);
            uintx2 u3 = *(const uintx2*)(Fb + (size_t)(p3 >> 16) * 64);
            float w0 = blo(p0), w1 = blo(p1), w2 = blo(p2), w3 = blo(p3);
            a0 += w0 * blo(u0.x); a1 += w0 * bhi(u0.x);
            a2 += w0 * blo(u0.y); a3 += w0 * bhi(u0.y);
            a0 += w1 * blo(u1.x); a1 += w1 * bhi(u1.x);
            a2 += w1 * blo(u1.y); a3 += w1 * bhi(u1.y);
            a0 += w2 * blo(u2.x); a1 += w2 * bhi(u2.x);
            a2 += w2 * blo(u2.y); a3 += w2 * bhi(u2.y);
            a0 += w3 * blo(u3.x); a1 += w3 * bhi(u3.x);
            a2 += w3 * blo(u3.y); a3 += w3 * bhi(u3.y);
        }
        for (; j < deg; ++j) {
            unsigned p = P[j];
            float w = blo(p);
            uintx2 u = *(const uintx2*)(Fb + (size_t)(p >> 16) * 64);
            a0 += w * blo(u.x); a1 += w * bhi(u.x);
            a2 += w * blo(u.y); a3 += w * bhi(u.y);
        }
        float inv = dinv1[n];
        f32x4 res = *(const f32x4*)&fcat[(size_t)n * 64 + 32 + ld * 4];
        f32x4 o;
        o.x = a0 * inv + res.x;
        o.y = a1 * inv + res.y;
        o.z = a2 * inv + res.z;
        o.w = a3 * inv + res.w;
        __builtin_nontemporal_store(o, (f32x4*)&out[(size_t)n * 32 + ld * 4]);
    }
}

extern "C" void kernel_launch(void* const* d_in, const int* in_sizes, int n_in,
                              void* d_out, int out_size, void* d_ws, size_t ws_size,
                              hipStream_t stream) {
    const float* x    = (const float*)d_in[0];
    const int*   src  = (const int*)d_in[1];
    const int*   dst  = (const int*)d_in[2];
    const float* W0   = (const float*)d_in[3];
    const float* al0  = (const float*)d_in[4];
    const float* ar0  = (const float*)d_in[5];
    const float* W1   = (const float*)d_in[6];
    const float* al1  = (const float*)d_in[7];
    const float* ar1  = (const float*)d_in[8];
    const float* Wres = (const float*)d_in[9];
    float* out = (float*)d_out;

    const int N = in_sizes[0] / 256;  // 50000
    const int E = in_sizes[1];        // 850000

    // workspace layout
    unsigned short* hbS   = (unsigned short*)d_ws;                // [8][N][32] bf16
    unsigned short* featS = hbS + (size_t)N * 256;                // [8][N][32] bf16
    unsigned short* W0P   = featS + (size_t)N * 256;              // [8][256][32] bf16
    unsigned short* Bt1   = W0P + 256 * 256;                      // 64*256 bf16
    unsigned short* fg16  = Bt1 + 64 * 256;                       // N*32 bf16
    float* fcat  = (float*)(fg16 + (size_t)N * 32);               // N*64 fp32
    float* el0   = fcat + (size_t)N * 64;                         // N*4
    float* er0   = el0 + (size_t)N * 4;                           // N*4
    float* el1   = er0 + (size_t)N * 4;                           // N
    float* er1   = el1 + N;                                       // N
    float* dinv0 = er1 + N;                                       // N*4
    float* dinv1 = dinv0 + (size_t)N * 4;                         // N
    unsigned* pk0 = (unsigned*)(dinv1 + N);                       // E*4 (4B packed, planar)
    unsigned* pk1 = pk0 + (size_t)E * 4;                          // E
    int*   deg    = (int*)(pk1 + E);                              // N
    int*   cursor = deg + N;                                      // N
    unsigned* gmax = (unsigned*)(cursor + N);                     // 16
    int*   offs  = (int*)(gmax + 16);                             // N+1
    int*   bsum  = offs + N + 1;                                  // 256
    int*   bpre  = bsum + 256;                                    // 256
    int*   csr_src = bpre + 256;                                  // E

    const int nb = (N + 255) / 256;
    const int eb = (E + 255) / 256;
    const int mb = (N + 63) / 64;

    // zero: deg, cursor, gmax (contiguous)
    hipMemsetAsync(deg, 0, (size_t)(2 * N + 16) * sizeof(int), stream);

    // prep (W0 panels + Bt1) fused with degree count
    prep_kernel<<<320 + eb, 256, 0, stream>>>(W0, W0P, W1, Wres, Bt1, dst, deg, E);

    // CSR
    scanA<<<nb, 256, 0, stream>>>(deg, bsum, N);
    scanB<<<1, 256, 0, stream>>>(bsum, bpre, nb);
    scanC<<<nb, 256, 0, stream>>>(deg, bpre, offs, N);
    scatter_kernel<<<eb, 256, 0, stream>>>(src, dst, offs, cursor, csr_src, E);

    // layer 0
    gemm0_all<<<mb, 256, 0, stream>>>(x, W0P, featS, el0, er0, al0, ar0, gmax, N);
    w0norm<<<(N + 15) / 16, 256, 0, stream>>>(el0, er0, gmax, offs, csr_src, pk0, dinv0, N, E);
    {
        int G = (N + 63) / 64;
        agg0_kernel<<<G * 8, 256, 0, stream>>>(featS, pk0, dinv0, offs, hbS, N, E);
    }

    // layer 1
    gemm1_fused<<<mb, 256, 0, stream>>>(hbS, Bt1, fcat, fg16, el1, er1, al1, ar1, gmax, N);
    w1norm<<<(N + 3) / 4, 256, 0, stream>>>(el1, er1, gmax, offs, csr_src, pk1, dinv1, N);
    {
        int G = (N + 31) / 32;
        agg1_kernel<<<G, 256, 0, stream>>>(fcat, fg16, pk1, dinv1, offs, out, N);
    }
}

// Round 18
// 264.869 us; speedup vs baseline: 1.0922x; 1.0922x over previous
//
#include <hip/hip_runtime.h>
#include <math.h>

#define NEG_SLOPE 0.2f

typedef __attribute__((ext_vector_type(8))) short short8;
typedef __attribute__((ext_vector_type(4))) float f32x4;
typedef unsigned int uintx2 __attribute__((ext_vector_type(2)));
typedef unsigned int uintx4 __attribute__((ext_vector_type(4)));

__device__ __forceinline__ float leaky(float x) { return x > 0.f ? x : NEG_SLOPE * x; }
__device__ __forceinline__ unsigned enc(float f) {
    unsigned u = __float_as_uint(f);
    return (u & 0x80000000u) ? ~u : (u | 0x80000000u);
}
__device__ __forceinline__ float dec(unsigned e) {
    return (e & 0x80000000u) ? __uint_as_float(e ^ 0x80000000u) : __uint_as_float(~e);
}
__device__ __forceinline__ unsigned bf16u(float f) {
    unsigned u = __float_as_uint(f);
    return (u + 0x7fffu + ((u >> 16) & 1u)) >> 16;
}
__device__ __forceinline__ float blo(unsigned u) { return __uint_as_float(u << 16); }
__device__ __forceinline__ float bhi(unsigned u) { return __uint_as_float(u & 0xffff0000u); }

// ---- prep: W0 -> panel-major bf16 W0P[8][256][32] | [W1|Wres]^T -> Bt1 | count ---
__global__ __launch_bounds__(256) void prep_kernel(const float* __restrict__ W0,
                                                   unsigned short* __restrict__ W0P,
                                                   const float* __restrict__ W1,
                                                   const float* __restrict__ Wres,
                                                   unsigned short* __restrict__ Bt1,
                                                   const int* __restrict__ dst,
                                                   int* __restrict__ deg, int E) {
    int b = blockIdx.x, tid = threadIdx.x;
    if (b < 256) {                        // W0P[k>>5][n][k&31] = W0[k][n]
        int n = b, k = tid;
        W0P[(k >> 5) * 8192 + n * 32 + (k & 31)] = (unsigned short)bf16u(W0[k * 256 + n]);
    } else if (b < 320) {                 // Bt1[n][k]
        int n = b - 256, k = tid;
        float v = (n < 32) ? W1[k * 32 + n] : Wres[k * 32 + (n - 32)];
        Bt1[n * 256 + k] = (unsigned short)bf16u(v);
    } else {                              // degree count
        int e = (b - 320) * 256 + tid;
        if (e < E) atomicAdd(&deg[dst[e]], 1);
    }
}

// ---- layer0 GEMM (round-8 structure; loads in-loop, no prefetch).
//      Epilogue tile ALIASES Bs (dead after K-loop) -> LDS 27.6KB. ----------------
__global__ __launch_bounds__(256) void gemm0_all(const float* __restrict__ x,
                                                 const unsigned short* __restrict__ W0P,
                                                 unsigned short* __restrict__ featS,
                                                 float* __restrict__ el0, float* __restrict__ er0,
                                                 const float* __restrict__ al,
                                                 const float* __restrict__ ar,
                                                 unsigned* __restrict__ gmax, int M) {
    __shared__ unsigned short As[64 * 40];
    __shared__ unsigned short Bs[256 * 40];     // K-loop B; epilogue: aliased as tile[64*72]
    __shared__ float sEl[4][64], sEr[4][64];
    unsigned short* tile = Bs;                  // alias: Bs dead after K-loop
    const int K = 256;
    int tid = threadIdx.x, lane = tid & 63, wv = tid >> 6;
    int m0 = blockIdx.x * 64;
    int wm = (wv >> 1) * 32, wn = (wv & 1) * 32;
    f32x4 acc[4][2][2] = {};
    int arow = tid >> 2, apart = tid & 3;
    bool avalid = (m0 + arow) < M;
    const float* Ap = x + (size_t)min(m0 + arow, M - 1) * K + apart * 8;

    for (int k0 = 0; k0 < K; k0 += 32) {
        // A: 8 fp32 -> 8 bf16 -> 16B LDS
        float4 a0 = avalid ? *(const float4*)(Ap + k0) : make_float4(0.f, 0.f, 0.f, 0.f);
        float4 a1 = avalid ? *(const float4*)(Ap + k0 + 4) : make_float4(0.f, 0.f, 0.f, 0.f);
        uint4 ap;
        ap.x = bf16u(a0.x) | (bf16u(a0.y) << 16);
        ap.y = bf16u(a0.z) | (bf16u(a0.w) << 16);
        ap.z = bf16u(a1.x) | (bf16u(a1.y) << 16);
        ap.w = bf16u(a1.z) | (bf16u(a1.w) << 16);
        *(uint4*)&As[arow * 40 + apart * 8] = ap;
        // B: coalesced 16KB panel (k-slab) -> Bs
        const unsigned short* slab = W0P + (k0 >> 5) * 8192;
#pragma unroll
        for (int p = 0; p < 4; ++p) {
            int q = p * 256 + tid;
            uint4 bv = *(const uint4*)(slab + q * 8);
            *(uint4*)&Bs[(q >> 2) * 40 + (q & 3) * 8] = bv;
        }
        __syncthreads();
        short8 af[2];
#pragma unroll
        for (int i = 0; i < 2; ++i)
            af[i] = *(const short8*)&As[(wm + i * 16 + (lane & 15)) * 40 + (lane >> 4) * 8];
#pragma unroll
        for (int y = 0; y < 4; ++y) {
            short8 bf[2];
#pragma unroll
            for (int j = 0; j < 2; ++j)
                bf[j] = *(const short8*)&Bs[(y * 64 + wn + j * 16 + (lane & 15)) * 40 + (lane >> 4) * 8];
#pragma unroll
            for (int i = 0; i < 2; ++i)
#pragma unroll
                for (int j = 0; j < 2; ++j)
                    acc[y][i][j] = __builtin_amdgcn_mfma_f32_16x16x32_bf16(af[i], bf[j], acc[y][i][j], 0, 0, 0);
        }
        __syncthreads();
    }
    size_t N32 = (size_t)M * 32;
#pragma unroll
    for (int y = 0; y < 4; ++y) {
#pragma unroll
        for (int i = 0; i < 2; ++i)
#pragma unroll
            for (int j = 0; j < 2; ++j)
#pragma unroll
                for (int r = 0; r < 4; ++r)
                    tile[(wm + i * 16 + (lane >> 4) * 4 + r) * 72 + wn + j * 16 + (lane & 15)] =
                        (unsigned short)bf16u(acc[y][i][j][r]);
        __syncthreads();
#pragma unroll
        for (int u = tid; u < 512; u += 256) {
            int ch = u >> 8, node = (u >> 2) & 63, part = u & 3;
            int row = m0 + node;
            if (row < M) {
                uint4 v = *(const uint4*)&tile[node * 72 + ch * 32 + part * 8];
                *(uint4*)&featS[(size_t)(2 * y + ch) * N32 + (size_t)row * 32 + part * 8] = v;
            }
        }
        {
            int row = tid >> 2, qr = tid & 3;
            float pe = 0.f, pr = 0.f;
            for (int k2 = 0; k2 < 16; ++k2) {
                int c = qr * 16 + k2;
                float f = __uint_as_float((unsigned)tile[row * 72 + c] << 16);
                pe += f * al[y * 64 + c];
                pr += f * ar[y * 64 + c];
            }
            pe += __shfl_xor(pe, 1); pe += __shfl_xor(pe, 2);
            pr += __shfl_xor(pr, 1); pr += __shfl_xor(pr, 2);
            if (qr == 0) {
                bool vv = (m0 + row) < M;
                if (vv) {
                    el0[(m0 + row) * 4 + y] = pe;
                    er0[(m0 + row) * 4 + y] = pr;
                }
                sEl[y][row] = vv ? pe : -1e30f;
                sEr[y][row] = vv ? pr : -1e30f;
            }
        }
        __syncthreads();
    }
    {
        float m1 = sEl[wv][lane];
        float m2 = sEr[wv][lane];
#pragma unroll
        for (int o = 1; o <= 32; o <<= 1) {
            m1 = fmaxf(m1, __shfl_xor(m1, o));
            m2 = fmaxf(m2, __shfl_xor(m2, o));
        }
        if (lane == 0) atomicMax(&gmax[wv], enc(m1));
        if (lane == 1) atomicMax(&gmax[4 + wv], enc(m2));
    }
}

// ---- layer1 GEMM (round-8 version VERBATIM) --------------------------------------
__global__ __launch_bounds__(256) void gemm1_fused(const unsigned short* __restrict__ hbS,
                                                   const unsigned short* __restrict__ Bt,
                                                   float* __restrict__ fcat,
                                                   unsigned short* __restrict__ fg16,
                                                   float* __restrict__ el1, float* __restrict__ er1,
                                                   const float* __restrict__ al,
                                                   const float* __restrict__ ar,
                                                   unsigned* __restrict__ gmax, int M) {
    __shared__ unsigned short As[64 * 40];
    __shared__ unsigned short Bs[64 * 40];
    __shared__ __align__(16) float tileF[64 * 68];
    __shared__ float sEl[64], sEr[64];
    const int K = 256;
    int tid = threadIdx.x, lane = tid & 63, wv = tid >> 6;
    int m0 = blockIdx.x * 64;
    int wm = (wv >> 1) * 32, wn = (wv & 1) * 32;
    f32x4 acc[2][2] = {};
    int srow = tid >> 2, scol = (tid & 3) * 8;
    bool avalid = (m0 + srow) < M;
    size_t arow = (size_t)min(m0 + srow, M - 1);
    size_t N32 = (size_t)M * 32;
    const unsigned short* Bp = Bt + (size_t)srow * K + scol;

    for (int k0 = 0; k0 < K; k0 += 32) {
        const unsigned short* Ap = hbS + (size_t)(k0 >> 5) * N32 + arow * 32 + scol;
        uint4 av = avalid ? *(const uint4*)Ap : make_uint4(0, 0, 0, 0);
        float4 bv = *(const float4*)(Bp + k0);
        *(uint4*)&As[srow * 40 + scol] = av;
        *(float4*)&Bs[srow * 40 + scol] = bv;
        __syncthreads();
        short8 af[2], bf[2];
#pragma unroll
        for (int i = 0; i < 2; ++i) {
            af[i] = *(const short8*)&As[(wm + i * 16 + (lane & 15)) * 40 + (lane >> 4) * 8];
            bf[i] = *(const short8*)&Bs[(wn + i * 16 + (lane & 15)) * 40 + (lane >> 4) * 8];
        }
#pragma unroll
        for (int i = 0; i < 2; ++i)
#pragma unroll
            for (int j = 0; j < 2; ++j)
                acc[i][j] = __builtin_amdgcn_mfma_f32_16x16x32_bf16(af[i], bf[j], acc[i][j], 0, 0, 0);
        __syncthreads();
    }
#pragma unroll
    for (int i = 0; i < 2; ++i)
#pragma unroll
        for (int j = 0; j < 2; ++j)
#pragma unroll
            for (int r = 0; r < 4; ++r)
                tileF[(wm + i * 16 + (lane >> 4) * 4 + r) * 68 + wn + j * 16 + (lane & 15)] =
                    acc[i][j][r];
    __syncthreads();
#pragma unroll
    for (int u = tid; u < 1024; u += 256) {
        int node = u >> 4, part = u & 15;
        int row = m0 + node;
        if (row < M)
            *(uint4*)&fcat[(size_t)row * 64 + part * 4] = *(const uint4*)&tileF[node * 68 + part * 4];
    }
    // fg16: bf16 copy of attended cols 0..31 (gather table for agg1)
#pragma unroll
    for (int u = tid; u < 1024; u += 256) {
        int node = u >> 4, part = u & 15;
        int row = m0 + node;
        if (row < M) {
            float f0 = tileF[node * 68 + part * 2];
            float f1 = tileF[node * 68 + part * 2 + 1];
            ((unsigned*)fg16)[(size_t)row * 16 + part] = bf16u(f0) | (bf16u(f1) << 16);
        }
    }
    {
        int row = tid >> 2, qr = tid & 3;
        float pe = 0.f, pr = 0.f;
        for (int k = 0; k < 8; ++k) {
            int c = qr * 8 + k;
            float f = tileF[row * 68 + c];
            pe += f * al[c];
            pr += f * ar[c];
        }
        pe += __shfl_xor(pe, 1); pe += __shfl_xor(pe, 2);
        pr += __shfl_xor(pr, 1); pr += __shfl_xor(pr, 2);
        if (qr == 0) {
            bool vv = (m0 + row) < M;
            if (vv) {
                el1[m0 + row] = pe;
                er1[m0 + row] = pr;
            }
            sEl[row] = vv ? pe : -1e30f;
            sEr[row] = vv ? pr : -1e30f;
        }
    }
    __syncthreads();
    if (tid < 64) {
        float m = sEl[tid];
#pragma unroll
        for (int o = 1; o <= 32; o <<= 1) m = fmaxf(m, __shfl_xor(m, o));
        if (tid == 0) atomicMax(&gmax[8], enc(m));
    } else if (tid < 128) {
        float m = sEr[tid - 64];
#pragma unroll
        for (int o = 1; o <= 32; o <<= 1) m = fmaxf(m, __shfl_xor(m, o));
        if (tid == 64) atomicMax(&gmax[9], enc(m));
    }
}

// ------------- CSR scans + scatter ------------------------------------------------
__global__ __launch_bounds__(256) void scanA(const int* __restrict__ deg, int* __restrict__ bsum, int N) {
    int i = blockIdx.x * 256 + threadIdx.x;
    int v = (i < N) ? deg[i] : 0;
#pragma unroll
    for (int o = 32; o > 0; o >>= 1) v += __shfl_xor(v, o);
    __shared__ int s[4];
    if ((threadIdx.x & 63) == 0) s[threadIdx.x >> 6] = v;
    __syncthreads();
    if (threadIdx.x == 0) bsum[blockIdx.x] = s[0] + s[1] + s[2] + s[3];
}

__global__ __launch_bounds__(256) void scanB(const int* __restrict__ bsum, int* __restrict__ bpre, int nb) {
    __shared__ int s[256];
    int t = threadIdx.x;
    int v = (t < nb) ? bsum[t] : 0;
    s[t] = v;
    __syncthreads();
    for (int o = 1; o < 256; o <<= 1) {
        int x = (t >= o) ? s[t - o] : 0;
        __syncthreads();
        s[t] += x;
        __syncthreads();
    }
    if (t < nb) bpre[t] = s[t] - v;
}

__global__ __launch_bounds__(256) void scanC(const int* __restrict__ deg, const int* __restrict__ bpre,
                                             int* __restrict__ off, int N) {
    int b = blockIdx.x, t = threadIdx.x;
    int i = b * 256 + t;
    int v = (i < N) ? deg[i] : 0;
    __shared__ int s[256];
    s[t] = v;
    __syncthreads();
    for (int o = 1; o < 256; o <<= 1) {
        int x = (t >= o) ? s[t - o] : 0;
        __syncthreads();
        s[t] += x;
        __syncthreads();
    }
    int incl = s[t];
    int base = bpre[b];
    if (i < N) off[i] = base + incl - v;
    if (i == N - 1) off[N] = base + incl;
}

__global__ void scatter_kernel(const int* __restrict__ src, const int* __restrict__ dst,
                               const int* __restrict__ off, int* __restrict__ cursor,
                               int* __restrict__ csr_src, int E) {
    int e = blockIdx.x * 256 + threadIdx.x;
    if (e < E) {
        int d = dst[e];
        int pos = atomicAdd(&cursor[d], 1);
        csr_src[off[d] + pos] = src[e];
    }
}

// ---- layer0 packed weights: pk0[h][idx] = (s<<16)|bf16(w); dinv per node/head ----
__global__ __launch_bounds__(256) void w0norm(const float* __restrict__ el,
                                              const float* __restrict__ er,
                                              const unsigned* __restrict__ gmax,
                                              const int* __restrict__ off,
                                              const int* __restrict__ csr_src,
                                              unsigned* __restrict__ pk0,
                                              float* __restrict__ dinv0, int N, int E) {
    int tid = threadIdx.x, lane = tid & 63, wv = tid >> 6;
    int grp = lane >> 4, j = lane & 15;
    float C0 = leaky(dec(gmax[0]) + dec(gmax[4]));
    float C1 = leaky(dec(gmax[1]) + dec(gmax[5]));
    float C2 = leaky(dec(gmax[2]) + dec(gmax[6]));
    float C3 = leaky(dec(gmax[3]) + dec(gmax[7]));
    int n = blockIdx.x * 16 + wv * 4 + grp;
    if (n >= N) return;
    int base = off[n], deg = off[n + 1] - base;
    float4 ern = *(const float4*)&er[n * 4];
    float d0 = 0.f, d1 = 0.f, d2 = 0.f, d3 = 0.f;
    for (int j0 = 0; j0 < deg; j0 += 16) {
        int jj = j0 + j;
        if (jj < deg) {
            int idx = base + jj;
            int s = csr_src[idx];
            float4 e4 = *(const float4*)&el[s * 4];
            unsigned b0 = bf16u(__expf(leaky(e4.x + ern.x) - C0));
            unsigned b1 = bf16u(__expf(leaky(e4.y + ern.y) - C1));
            unsigned b2 = bf16u(__expf(leaky(e4.z + ern.z) - C2));
            unsigned b3 = bf16u(__expf(leaky(e4.w + ern.w) - C3));
            unsigned sh = (unsigned)s << 16;
            pk0[idx] = sh | b0;
            pk0[E + idx] = sh | b1;
            pk0[2 * E + idx] = sh | b2;
            pk0[3 * E + idx] = sh | b3;
            d0 += __uint_as_float(b0 << 16);
            d1 += __uint_as_float(b1 << 16);
            d2 += __uint_as_float(b2 << 16);
            d3 += __uint_as_float(b3 << 16);
        }
    }
#pragma unroll
    for (int o = 1; o <= 8; o <<= 1) {
        d0 += __shfl_xor(d0, o);
        d1 += __shfl_xor(d1, o);
        d2 += __shfl_xor(d2, o);
        d3 += __shfl_xor(d3, o);
    }
    if (j == 0) {
        float4 iv = make_float4(1.f / d0, 1.f / d1, 1.f / d2, 1.f / d3);
        *(float4*)&dinv0[n * 4] = iv;
    }
}

// ---- layer1 packed weights: pk1[idx] = (s<<16)|bf16(w) --------------------------
__global__ __launch_bounds__(256) void w1norm(const float* __restrict__ el,
                                              const float* __restrict__ er,
                                              const unsigned* __restrict__ gmax,
                                              const int* __restrict__ off,
                                              const int* __restrict__ csr_src,
                                              unsigned* __restrict__ pk1,
                                              float* __restrict__ dinv1, int N) {
    int tid = threadIdx.x, lane = tid & 63, wv = tid >> 6;
    float C = leaky(dec(gmax[8]) + dec(gmax[9]));
    int n = blockIdx.x * 4 + wv;
    if (n >= N) return;
    int base = off[n], deg = off[n + 1] - base;
    float ern = er[n];
    float den = 0.f;
    for (int j0 = 0; j0 < deg; j0 += 64) {
        int jj = j0 + lane;
        if (jj < deg) {
            int idx = base + jj;
            int s = csr_src[idx];
            unsigned b = bf16u(__expf(leaky(el[s] + ern) - C));
            pk1[idx] = ((unsigned)s << 16) | b;
            den += __uint_as_float(b << 16);
        }
    }
#pragma unroll
    for (int o = 1; o <= 32; o <<= 1) den += __shfl_xor(den, o);
    if (lane == 0) dinv1[n] = 1.f / den;
}

// ---- layer0 aggregation: 4-lane group per node-chunk; packed pk; 4x unroll ------
__global__ __launch_bounds__(256) void agg0_kernel(const unsigned short* __restrict__ featS,
                                                   const unsigned* __restrict__ pk0,
                                                   const float* __restrict__ dinv0,
                                                   const int* __restrict__ off,
                                                   unsigned short* __restrict__ hbS, int N, int E) {
    int tid = threadIdx.x;
    int c = blockIdx.x & 7, h = c >> 1;
    int gblk = blockIdx.x >> 3, G = gridDim.x >> 3;
    int grp = tid >> 2, ld = tid & 3;    // 64 groups x 4 lanes; lane covers 8 dims
    size_t N32 = (size_t)N * 32;
    const char* Fb = (const char*)(featS + (size_t)c * N32) + ld * 16;
    const unsigned* PH = pk0 + (size_t)h * E;
    for (int n = gblk * 64 + grp; n < N; n += G * 64) {
        int base = off[n], deg = off[n + 1] - base;
        float a0 = 0.f, a1 = 0.f, a2 = 0.f, a3 = 0.f;
        float a4 = 0.f, a5 = 0.f, a6 = 0.f, a7 = 0.f;
        const unsigned* P = PH + base;
        int j = 0;
        for (; j + 4 <= deg; j += 4) {
            unsigned p0 = P[j], p1 = P[j + 1], p2 = P[j + 2], p3 = P[j + 3];
            uintx4 u0 = *(const uintx4*)(Fb + (size_t)(p0 >> 16) * 64);
            uintx4 u1 = *(const uintx4*)(Fb + (size_t)(p1 >> 16) * 64);
            uintx4 u2 = *(const uintx4*)(Fb + (size_t)(p2 >> 16) * 64);
            uintx4 u3 = *(const uintx4*)(Fb + (size_t)(p3 >> 16) * 64);
            float w0 = blo(p0), w1 = blo(p1), w2 = blo(p2), w3 = blo(p3);
            a0 += w0 * blo(u0.x); a1 += w0 * bhi(u0.x);
            a2 += w0 * blo(u0.y); a3 += w0 * bhi(u0.y);
            a4 += w0 * blo(u0.z); a5 += w0 * bhi(u0.z);
            a6 += w0 * blo(u0.w); a7 += w0 * bhi(u0.w);
            a0 += w1 * blo(u1.x); a1 += w1 * bhi(u1.x);
            a2 += w1 * blo(u1.y); a3 += w1 * bhi(u1.y);
            a4 += w1 * blo(u1.z); a5 += w1 * bhi(u1.z);
            a6 += w1 * blo(u1.w); a7 += w1 * bhi(u1.w);
            a0 += w2 * blo(u2.x); a1 += w2 * bhi(u2.x);
            a2 += w2 * blo(u2.y); a3 += w2 * bhi(u2.y);
            a4 += w2 * blo(u2.z); a5 += w2 * bhi(u2.z);
            a6 += w2 * blo(u2.w); a7 += w2 * bhi(u2.w);
            a0 += w3 * blo(u3.x); a1 += w3 * bhi(u3.x);
            a2 += w3 * blo(u3.y); a3 += w3 * bhi(u3.y);
            a4 += w3 * blo(u3.z); a5 += w3 * bhi(u3.z);
            a6 += w3 * blo(u3.w); a7 += w3 * bhi(u3.w);
        }
        for (; j < deg; ++j) {
            unsigned p = P[j];
            float w = blo(p);
            uintx4 u = *(const uintx4*)(Fb + (size_t)(p >> 16) * 64);
            a0 += w * blo(u.x); a1 += w * bhi(u.x);
            a2 += w * blo(u.y); a3 += w * bhi(u.y);
            a4 += w * blo(u.z); a5 += w * bhi(u.z);
            a6 += w * blo(u.w); a7 += w * bhi(u.w);
        }
        float inv = dinv0[n * 4 + h];
        float v0 = a0 * inv, v1 = a1 * inv, v2 = a2 * inv, v3 = a3 * inv;
        float v4 = a4 * inv, v5 = a5 * inv, v6 = a6 * inv, v7 = a7 * inv;
        v0 = v0 > 0.f ? v0 : (__expf(v0) - 1.f);
        v1 = v1 > 0.f ? v1 : (__expf(v1) - 1.f);
        v2 = v2 > 0.f ? v2 : (__expf(v2) - 1.f);
        v3 = v3 > 0.f ? v3 : (__expf(v3) - 1.f);
        v4 = v4 > 0.f ? v4 : (__expf(v4) - 1.f);
        v5 = v5 > 0.f ? v5 : (__expf(v5) - 1.f);
        v6 = v6 > 0.f ? v6 : (__expf(v6) - 1.f);
        v7 = v7 > 0.f ? v7 : (__expf(v7) - 1.f);
        uintx4 o;
        o.x = bf16u(v0) | (bf16u(v1) << 16);
        o.y = bf16u(v2) | (bf16u(v3) << 16);
        o.z = bf16u(v4) | (bf16u(v5) << 16);
        o.w = bf16u(v6) | (bf16u(v7) << 16);
        __builtin_nontemporal_store(o, (uintx4*)&hbS[(size_t)c * N32 + (size_t)n * 32 + ld * 8]);
    }
}

// ---- layer1 aggregation + residual: 8-lane group per node, packed pk ------------
__global__ __launch_bounds__(256) void agg1_kernel(const float* __restrict__ fcat,
                                                   const unsigned short* __restrict__ fg16,
                                                   const unsigned* __restrict__ pk1,
                                                   const float* __restrict__ dinv1,
                                                   const int* __restrict__ off,
                                                   float* __restrict__ out, int N) {
    int tid = threadIdx.x;
    int grp = tid >> 3, ld = tid & 7;    // 32 groups x 8 lanes; lane covers 4 dims
    const char* Fb = (const char*)fg16 + ld * 8;
    for (int n = blockIdx.x * 32 + grp; n < N; n += gridDim.x * 32) {
        int base = off[n], deg = off[n + 1] - base;
        float a0 = 0.f, a1 = 0.f, a2 = 0.f, a3 = 0.f;
        const unsigned* P = pk1 + base;
        int j = 0;
        for (; j + 4 <= deg; j += 4) {
            unsigned p0 = P[j], p1 = P[j + 1], p2 = P[j + 2], p3 = P[j + 3];
            uintx2 u0 = *(const uintx2*)(Fb + (size_t)(p0 >> 16) * 64);
            uintx2 u1 = *(const uintx2*)(Fb + (size_t)(p1 >> 16) * 64);
            uintx2 u2 = *(const uintx2*)(Fb + (size_t)(p2 >> 16) * 64);
            uintx2 u3 = *(const uintx2*)(Fb + (size_t)(p3 >> 16) * 64);
            float w0 = blo(p0), w1 = blo(p1), w2 = blo(p2), w3 = blo(p3);
            a0 += w0 * blo(u0.x); a1 += w0 * bhi(u0.x);
            a2 += w0 * blo(u0.y); a3 += w0 * bhi(u0.y);
            a0 += w1 * blo(u1.x); a1 += w1 * bhi(u1.x);
            a2 += w1 * blo(u1.y); a3 += w1 * bhi(u1.y);
            a0 += w2 * blo(u2.x); a1 += w2 * bhi(u2.x);
            a2 += w2 * blo(u2.y); a3 += w2 * bhi(u2.y);
            a0 += w3 * blo(u3.x); a1 += w3 * bhi(u3.x);
            a2 += w3 * blo(u3.y); a3 += w3 * bhi(u3.y);
        }
        for (; j < deg; ++j) {
            unsigned p = P[j];
            float w = blo(p);
            uintx2 u = *(const uintx2*)(Fb + (size_t)(p >> 16) * 64);
            a0 += w * blo(u.x); a1 += w * bhi(u.x);
            a2 += w * blo(u.y); a3 += w * bhi(u.y);
        }
        float inv = dinv1[n];
        f32x4 res = *(const f32x4*)&fcat[(size_t)n * 64 + 32 + ld * 4];
        f32x4 o;
        o.x = a0 * inv + res.x;
        o.y = a1 * inv + res.y;
        o.z = a2 * inv + res.z;
        o.w = a3 * inv + res.w;
        __builtin_nontemporal_store(o, (f32x4*)&out[(size_t)n * 32 + ld * 4]);
    }
}

extern "C" void kernel_launch(void* const* d_in, const int* in_sizes, int n_in,
                              void* d_out, int out_size, void* d_ws, size_t ws_size,
                              hipStream_t stream) {
    const float* x    = (const float*)d_in[0];
    const int*   src  = (const int*)d_in[1];
    const int*   dst  = (const int*)d_in[2];
    const float* W0   = (const float*)d_in[3];
    const float* al0  = (const float*)d_in[4];
    const float* ar0  = (const float*)d_in[5];
    const float* W1   = (const float*)d_in[6];
    const float* al1  = (const float*)d_in[7];
    const float* ar1  = (const float*)d_in[8];
    const float* Wres = (const float*)d_in[9];
    float* out = (float*)d_out;

    const int N = in_sizes[0] / 256;  // 50000
    const int E = in_sizes[1];        // 850000

    // workspace layout
    unsigned short* hbS   = (unsigned short*)d_ws;                // [8][N][32] bf16
    unsigned short* featS = hbS + (size_t)N * 256;                // [8][N][32] bf16
    unsigned short* W0P   = featS + (size_t)N * 256;              // [8][256][32] bf16
    unsigned short* Bt1   = W0P + 256 * 256;                      // 64*256 bf16
    unsigned short* fg16  = Bt1 + 64 * 256;                       // N*32 bf16
    float* fcat  = (float*)(fg16 + (size_t)N * 32);               // N*64 fp32
    float* el0   = fcat + (size_t)N * 64;                         // N*4
    float* er0   = el0 + (size_t)N * 4;                           // N*4
    float* el1   = er0 + (size_t)N * 4;                           // N
    float* er1   = el1 + N;                                       // N
    float* dinv0 = er1 + N;                                       // N*4
    float* dinv1 = dinv0 + (size_t)N * 4;                         // N
    unsigned* pk0 = (unsigned*)(dinv1 + N);                       // E*4 (4B packed, planar)
    unsigned* pk1 = pk0 + (size_t)E * 4;                          // E
    int*   deg    = (int*)(pk1 + E);                              // N
    int*   cursor = deg + N;                                      // N
    unsigned* gmax = (unsigned*)(cursor + N);                     // 16
    int*   offs  = (int*)(gmax + 16);                             // N+1
    int*   bsum  = offs + N + 1;                                  // 256
    int*   bpre  = bsum + 256;                                    // 256
    int*   csr_src = bpre + 256;                                  // E

    const int nb = (N + 255) / 256;
    const int eb = (E + 255) / 256;
    const int mb = (N + 63) / 64;

    // zero: deg, cursor, gmax (contiguous)
    hipMemsetAsync(deg, 0, (size_t)(2 * N + 16) * sizeof(int), stream);

    // prep (W0 panels + Bt1) fused with degree count
    prep_kernel<<<320 + eb, 256, 0, stream>>>(W0, W0P, W1, Wres, Bt1, dst, deg, E);

    // CSR
    scanA<<<nb, 256, 0, stream>>>(deg, bsum, N);
    scanB<<<1, 256, 0, stream>>>(bsum, bpre, nb);
    scanC<<<nb, 256, 0, stream>>>(deg, bpre, offs, N);
    scatter_kernel<<<eb, 256, 0, stream>>>(src, dst, offs, cursor, csr_src, E);

    // layer 0
    gemm0_all<<<mb, 256, 0, stream>>>(x, W0P, featS, el0, er0, al0, ar0, gmax, N);
    w0norm<<<(N + 15) / 16, 256, 0, stream>>>(el0, er0, gmax, offs, csr_src, pk0, dinv0, N, E);
    {
        int G = (N + 63) / 64;
        agg0_kernel<<<G * 8, 256, 0, stream>>>(featS, pk0, dinv0, offs, hbS, N, E);
    }

    // layer 1
    gemm1_fused<<<mb, 256, 0, stream>>>(hbS, Bt1, fcat, fg16, el1, er1, al1, ar1, gmax, N);
    w1norm<<<(N + 3) / 4, 256, 0, stream>>>(el1, er1, gmax, offs, csr_src, pk1, dinv1, N);
    {
        int G = (N + 31) / 32;
        agg1_kernel<<<G, 256, 0, stream>>>(fcat, fg16, pk1, dinv1, offs, out, N);
    }
}